// Round 13
// baseline (5693.777 us; speedup 1.0000x reference)
//
#include <hip/hip_runtime.h>
#include <math.h>

#define N_NODES 100000
#define N_EDGES 1200000
#define N_GRAPHS 16
#define CH 64
#define HEADS 4
#define GL 6
#define IN_DIM 261
#define GDIM 24
#define LIN 32
#define LL 3
#define EPSN 1e-5f
#define MPART 64           // moment partial copies
#define RNG (N_NODES / 8)  // 12500 nodes per dst-range
#define EBLK 25000         // edge_agg blocks (= N_NODES/4), 8*3125

typedef unsigned short u16;
typedef unsigned char u8;
typedef __attribute__((ext_vector_type(8))) short bf16x8;
typedef __attribute__((ext_vector_type(4))) float f32x4;

__device__ __forceinline__ u16 f2bf(float f) {
  unsigned u = __float_as_uint(f);
  u = (u + 0x7FFFu + ((u >> 16) & 1u)) >> 16;
  return (u16)u;
}
__device__ __forceinline__ float bf2f(u16 v) {
  return __uint_as_float(((unsigned)v) << 16);
}
// OCP e4m3 via gfx950 HW converts
__device__ __forceinline__ u8 f2fp8(float f) {
  int r = __builtin_amdgcn_cvt_pk_fp8_f32(f, f, 0, false);
  return (u8)(r & 0xff);
}
__device__ __forceinline__ float fp82f(int b) {
  return __builtin_amdgcn_cvt_f32_fp8(b, 0);
}

__device__ __forceinline__ float gelu_exact(float x) {
  return 0.5f * x * (1.0f + erff(x * 0.70710678118654752440f));
}

__device__ __forceinline__ float ln32(float x, float w, float b) {
  float m = x;
  m += __shfl_xor(m, 1); m += __shfl_xor(m, 2); m += __shfl_xor(m, 4);
  m += __shfl_xor(m, 8); m += __shfl_xor(m, 16);
  m *= (1.0f / 32.0f);
  float d = x - m;
  float v = d * d;
  v += __shfl_xor(v, 1); v += __shfl_xor(v, 2); v += __shfl_xor(v, 4);
  v += __shfl_xor(v, 8); v += __shfl_xor(v, 16);
  v *= (1.0f / 32.0f);
  return d * rsqrtf(v + EPSN) * w + b;
}

// ---------------- setup: CSR build, dst-range partitioned ----------------
__global__ void k_count_part(const int* __restrict__ dst, int* __restrict__ deg) {
  const int range = blockIdx.x & 7;
  const int sub = blockIdx.x >> 3;
  const int lo = range * RNG, hi = lo + RNG;
  for (int e = sub * 256 + threadIdx.x; e < N_EDGES; e += 256 * 256) {
    int d = dst[e];
    if (d >= lo && d < hi) atomicAdd(&deg[d], 1);
  }
}

__global__ void k_scatter_part(const int* __restrict__ src, const int* __restrict__ dst,
                               int* __restrict__ cur, int* __restrict__ ssrc) {
  const int range = blockIdx.x & 7;
  const int sub = blockIdx.x >> 3;
  const int lo = range * RNG, hi = lo + RNG;
  for (int e = sub * 256 + threadIdx.x; e < N_EDGES; e += 256 * 256) {
    int d = dst[e];
    if (d >= lo && d < hi) {
      int p = atomicAdd(&cur[d], 1);
      ssrc[p] = src[e];
    }
  }
}

__global__ void k_block_sums(const int* __restrict__ deg, int* __restrict__ bsum) {
  __shared__ int sh[256];
  int i = blockIdx.x * 256 + threadIdx.x;
  sh[threadIdx.x] = (i < N_NODES) ? deg[i] : 0;
  __syncthreads();
  for (int s = 128; s > 0; s >>= 1) {
    if (threadIdx.x < s) sh[threadIdx.x] += sh[threadIdx.x + s];
    __syncthreads();
  }
  if (threadIdx.x == 0) bsum[blockIdx.x] = sh[0];
}

__global__ void k_scan_bsums(int* __restrict__ bsum, int nb, int* __restrict__ off) {
  __shared__ int sh[512];
  int i = threadIdx.x;
  int v = (i < nb) ? bsum[i] : 0;
  sh[i] = v;
  __syncthreads();
  for (int s = 1; s < 512; s <<= 1) {
    int t = (i >= s) ? sh[i - s] : 0;
    __syncthreads();
    sh[i] += t;
    __syncthreads();
  }
  if (i < nb) bsum[i] = sh[i] - v;
  if (i == nb - 1) off[N_NODES] = sh[i];
}

__global__ void k_scan_final(const int* __restrict__ deg, const int* __restrict__ bsum,
                             int* __restrict__ off, int* __restrict__ cur) {
  __shared__ int sh[256];
  int i = blockIdx.x * 256 + threadIdx.x;
  int v = (i < N_NODES) ? deg[i] : 0;
  sh[threadIdx.x] = v;
  __syncthreads();
  for (int s = 1; s < 256; s <<= 1) {
    int t = (threadIdx.x >= s) ? sh[threadIdx.x - s] : 0;
    __syncthreads();
    sh[threadIdx.x] += t;
    __syncthreads();
  }
  if (i < N_NODES) {
    int ex = bsum[blockIdx.x] + sh[threadIdx.x] - v;
    off[i] = ex;
    cur[i] = ex;
  }
}

__global__ void k_graph_starts(const int* __restrict__ batch, int* __restrict__ gstart) {
  int g = threadIdx.x;
  if (g > N_GRAPHS) return;
  int lo = 0, hi = N_NODES;
  while (lo < hi) {
    int mid = (lo + hi) >> 1;
    if (batch[mid] < g) lo = mid + 1; else hi = mid;
  }
  gstart[g] = lo;
}

// ---------------- weight prep: fp32 -> bf16 B-fragment swizzle ----------------
#define W0S_ELEMS (4 * 9 * 64 * 8)
#define WGS_ELEMS (4 * 2 * 64 * 8)
__global__ void k_prep_w(const float* __restrict__ W0, const float* __restrict__ Wg,
                         u16* __restrict__ W0s, u16* __restrict__ Wgs) {
  int idx = blockIdx.x * 256 + threadIdx.x;
  if (idx < W0S_ELEMS) {
    int i = idx & 7, lane = (idx >> 3) & 63, ks = (idx >> 9) % 9, cb = idx / (9 * 512);
    int k = ks * 32 + (lane >> 4) * 8 + i, c = cb * 16 + (lane & 15);
    W0s[idx] = f2bf(k < IN_DIM ? W0[k * 64 + c] : 0.f);
  } else if (idx < W0S_ELEMS + GL * WGS_ELEMS) {
    int j = idx - W0S_ELEMS;
    int l = j / WGS_ELEMS, p = j % WGS_ELEMS;
    int i = p & 7, lane = (p >> 3) & 63, ks = (p >> 9) & 1, cb = p / (2 * 512);
    int k = ks * 32 + (lane >> 4) * 8 + i, c = cb * 16 + (lane & 15);
    Wgs[j] = f2bf(Wg[(size_t)l * 4096 + k * 64 + c]);
  }
}

// ---------------- layer 0: standalone MFMA GEMM + logits (fp8 T out) ----------------
__global__ __launch_bounds__(256) void k_gemm0(
    const float* __restrict__ Xin, const u16* __restrict__ Wswz,
    const float* __restrict__ a_src, const float* __restrict__ a_dst,
    u8* __restrict__ T8, float* __restrict__ ES, float* __restrict__ ED) {
  const int lane = threadIdx.x & 63;
  const int wid = (blockIdx.x << 2) + (threadIdx.x >> 6);
  const int NT = N_NODES / 16;
  if (wid >= NT) return;
  const int grp = lane >> 4, n16 = lane & 15;
  float as_l[4], ad_l[4];
  #pragma unroll
  for (int cb = 0; cb < 4; ++cb) {
    as_l[cb] = a_src[cb * 16 + n16];
    ad_l[cb] = a_dst[cb * 16 + n16];
  }
  const long r0 = (long)wid * 16;

  bf16x8 afr[9];
  const float* xr = Xin + (r0 + n16) * (size_t)IN_DIM;
  #pragma unroll
  for (int ks = 0; ks < 9; ++ks) {
    bf16x8 a;
    #pragma unroll
    for (int i = 0; i < 8; ++i) {
      int k = ks * 32 + grp * 8 + i;
      float v = (k < IN_DIM) ? xr[k] : 0.f;
      a[i] = (short)f2bf(v);
    }
    afr[ks] = a;
  }

  #pragma unroll
  for (int cb = 0; cb < 4; ++cb) {
    f32x4 a = {0.f, 0.f, 0.f, 0.f};
    #pragma unroll
    for (int ks = 0; ks < 9; ++ks) {
      bf16x8 b = *(const bf16x8*)(Wswz + ((size_t)(cb * 9 + ks) * 64 + lane) * 8);
      a = __builtin_amdgcn_mfma_f32_16x16x32_bf16(afr[ks], b, a, 0, 0, 0);
    }
    #pragma unroll
    for (int r = 0; r < 4; ++r) {
      const long row = r0 + grp * 4 + r;
      float v = a[r];
      T8[row * 64 + cb * 16 + n16] = f2fp8(v);
      float s = v * as_l[cb];
      float d = v * ad_l[cb];
      s += __shfl_xor(s, 1); s += __shfl_xor(s, 2); s += __shfl_xor(s, 4); s += __shfl_xor(s, 8);
      d += __shfl_xor(d, 1); d += __shfl_xor(d, 2); d += __shfl_xor(d, 4); d += __shfl_xor(d, 8);
      if (n16 == 0) {
        ES[row * 4 + cb] = s;
        ED[row * 4 + cb] = d;
      }
    }
  }
}

// ---------------- edge softmax + aggregate + moment partials + fused stats ----------------
__global__ __launch_bounds__(256) void k_edge_agg(
    const u8* __restrict__ T8, const float* __restrict__ ES, const float* __restrict__ ED,
    const int* __restrict__ off, const int* __restrict__ ssrc,
    const float* __restrict__ bias, const int* __restrict__ batch,
    const int* __restrict__ gstart, const float* __restrict__ ms,
    u16* __restrict__ Fb, float* __restrict__ SPp, float* __restrict__ SQp,
    float* __restrict__ MM, float* __restrict__ IS, int* __restrict__ cnt) {
  __shared__ float sF[4][64];
  __shared__ float sQ[4][64];
  __shared__ int lastdone;
  const int lane = threadIdx.x & 63;
  const int wv = threadIdx.x >> 6;
  // XCD-chunked swizzle: 25000 blocks = 8 * 3125
  const int bid = (blockIdx.x & 7) * (EBLK / 8) + (blockIdx.x >> 3);
  const int n = bid * 4 + wv;
  const int e0 = off[n];
  const int ec = off[n + 1] - e0;
  const int hd = lane & 3;
  const int qh = lane >> 4;
  const u8* Tl = T8 + lane;
  const float tself = fp82f(Tl[(long)n * 64]);   // issue early
  const float ed_h = ED[n * 4 + hd];
  float x0 = ES[n * 4 + hd] + ed_h;
  x0 = fmaxf(x0, 0.2f * x0);
  const float p0 = __expf(fminf(x0, 25.f));
  float s_run = p0;
  float acc = __shfl(p0, qh) * tself;
  for (int base = 0; base < ec; base += 16) {
    const int eidx = base + (lane >> 2);
    const bool valid = eidx < ec;
    const int sv = valid ? ssrc[e0 + eidx] : n;
    int rows[16];
    #pragma unroll
    for (int e = 0; e < 16; ++e) rows[e] = __shfl(sv, e << 2);
    int tvb[16];
    #pragma unroll
    for (int e = 0; e < 16; ++e) tvb[e] = Tl[(long)rows[e] * 64];
    float v = ES[sv * 4 + hd] + ed_h;
    v = fmaxf(v, 0.2f * v);
    const float p = valid ? __expf(fminf(v, 25.f)) : 0.f;
    float ps = p;
    ps += __shfl_xor(ps, 4); ps += __shfl_xor(ps, 8);
    ps += __shfl_xor(ps, 16); ps += __shfl_xor(ps, 32);
    s_run += ps;
    #pragma unroll
    for (int e = 0; e < 16; ++e)
      acc = fmaf(__shfl(p, (e << 2) | qh), fp82f(tvb[e]), acc);
  }
  const float s_q = __shfl(s_run, qh);
  const float o = acc / (s_q + 1e-16f) + bias[lane];
  const float f = gelu_exact(o);
  Fb[(long)n * 64 + lane] = f2bf(f);
  sF[wv][lane] = f;
  sQ[wv][lane] = f * f;
  __syncthreads();
  // per-block LDS reduce, one atomic pair per graph-run (typically 1 run)
  if (threadIdx.x < 64) {
    const int part = bid & (MPART - 1);
    const long nb = (long)bid * 4;
    int gprev = batch[nb];
    float fs = 0.f, qs = 0.f;
    #pragma unroll
    for (int w2 = 0; w2 < 4; ++w2) {
      int gw = batch[nb + w2];
      if (gw != gprev) {
        atomicAdd(&SPp[((size_t)part * N_GRAPHS + gprev) * 64 + threadIdx.x], fs);
        atomicAdd(&SQp[((size_t)part * N_GRAPHS + gprev) * 64 + threadIdx.x], qs);
        fs = 0.f; qs = 0.f; gprev = gw;
      }
      fs += sF[w2][threadIdx.x];
      qs += sQ[w2][threadIdx.x];
    }
    atomicAdd(&SPp[((size_t)part * N_GRAPHS + gprev) * 64 + threadIdx.x], fs);
    atomicAdd(&SQp[((size_t)part * N_GRAPHS + gprev) * 64 + threadIdx.x], qs);
  }
  __syncthreads();
  // last-block-done ticket -> compute MM/IS and re-zero partials (round-8 pattern)
  if (threadIdx.x == 0) {
    __threadfence();
    lastdone = (atomicAdd(cnt, 1) == EBLK - 1) ? 1 : 0;
  }
  __syncthreads();
  if (lastdone) {
    __threadfence();
    const int c = threadIdx.x & 63, chunk = threadIdx.x >> 6;
    for (int g = 0; g < N_GRAPHS; ++g) {
      float s = 0.f, q = 0.f;
      for (int p2 = chunk; p2 < MPART; p2 += 4) {
        size_t i = ((size_t)p2 * N_GRAPHS + g) * 64 + c;
        s += SPp[i]; SPp[i] = 0.f;    // fold re-zero into the read pass
        q += SQp[i]; SQp[i] = 0.f;
      }
      sF[chunk][c] = s;
      sQ[chunk][c] = q;
      __syncthreads();
      if (threadIdx.x < 64) {
        s = sF[0][c] + sF[1][c] + sF[2][c] + sF[3][c];
        q = sQ[0][c] + sQ[1][c] + sQ[2][c] + sQ[3][c];
        float cntf = fmaxf((float)(gstart[g + 1] - gstart[g]), 1.0f);
        float mean = s / cntf;
        float mm = mean * ms[c];
        float var = q / cntf - 2.f * mm * mean + mm * mm;
        MM[g * 64 + c] = mm;
        IS[g * 64 + c] = rsqrtf(fmaxf(var, 0.f) + EPSN);
      }
      __syncthreads();
    }
    if (threadIdx.x == 0) *cnt = 0;
  }
}

// ---------------- fused: GraphNorm + residual (bf16 X) + NEXT layer's GEMM + logits ----------------
__global__ __launch_bounds__(256) void k_norm_gemm(
    const u16* __restrict__ Fb, const int* __restrict__ batch,
    const float* __restrict__ MM, const float* __restrict__ IS,
    const float* __restrict__ w, const float* __restrict__ b,
    const u16* __restrict__ Wswz, const float* __restrict__ a_src,
    const float* __restrict__ a_dst, u16* __restrict__ Xb, int residual,
    u8* __restrict__ T8, float* __restrict__ ES, float* __restrict__ ED) {
  __shared__ __align__(16) u16 sY[16][72];   // 144B rows: 16B-aligned
  const int tid = threadIdx.x;
  const long n0 = (long)blockIdx.x * 16;
  {
    const int node = tid >> 4;
    const int c4 = (tid & 15) << 2;
    const long n = n0 + node;
    const int g = batch[n];
    ushort4 fu = *(const ushort4*)(Fb + n * 64 + c4);
    float4 f = make_float4(bf2f(fu.x), bf2f(fu.y), bf2f(fu.z), bf2f(fu.w));
    float4 mm = *(const float4*)(MM + g * 64 + c4);
    float4 is = *(const float4*)(IS + g * 64 + c4);
    float4 wv = *(const float4*)(w + c4);
    float4 bv = *(const float4*)(b + c4);
    float4 y;
    y.x = fmaf(wv.x * (f.x - mm.x), is.x, bv.x);
    y.y = fmaf(wv.y * (f.y - mm.y), is.y, bv.y);
    y.z = fmaf(wv.z * (f.z - mm.z), is.z, bv.z);
    y.w = fmaf(wv.w * (f.w - mm.w), is.w, bv.w);
    if (residual) {
      ushort4 xo = *(const ushort4*)(Xb + n * 64 + c4);
      y.x += bf2f(xo.x); y.y += bf2f(xo.y); y.z += bf2f(xo.z); y.w += bf2f(xo.w);
    }
    union { u16 s[4]; unsigned long long ll; } pk;
    pk.s[0] = f2bf(y.x); pk.s[1] = f2bf(y.y); pk.s[2] = f2bf(y.z); pk.s[3] = f2bf(y.w);
    *(unsigned long long*)(Xb + n * 64 + c4) = pk.ll;
    *(unsigned long long*)&sY[node][c4] = pk.ll;
  }
  __syncthreads();
  const int lane = tid & 63;
  const int wid = tid >> 6;
  const int grp = lane >> 4, n16 = lane & 15;
  bf16x8 afr[2];
  #pragma unroll
  for (int ks = 0; ks < 2; ++ks)
    afr[ks] = *(const bf16x8*)(&sY[n16][ks * 32 + grp * 8]);
  f32x4 a = {0.f, 0.f, 0.f, 0.f};
  #pragma unroll
  for (int ks = 0; ks < 2; ++ks) {
    bf16x8 bb = *(const bf16x8*)(Wswz + ((size_t)(wid * 2 + ks) * 64 + lane) * 8);
    a = __builtin_amdgcn_mfma_f32_16x16x32_bf16(afr[ks], bb, a, 0, 0, 0);
  }
  const float as_c = a_src[wid * 16 + n16];
  const float ad_c = a_dst[wid * 16 + n16];
  #pragma unroll
  for (int r = 0; r < 4; ++r) {
    const long row = n0 + grp * 4 + r;
    float v = a[r];
    T8[row * 64 + wid * 16 + n16] = f2fp8(v);
    float s = v * as_c;
    float d = v * ad_c;
    s += __shfl_xor(s, 1); s += __shfl_xor(s, 2); s += __shfl_xor(s, 4); s += __shfl_xor(s, 8);
    d += __shfl_xor(d, 1); d += __shfl_xor(d, 2); d += __shfl_xor(d, 4); d += __shfl_xor(d, 8);
    if (n16 == 0) {
      ES[row * 4 + wid] = s;
      ED[row * 4 + wid] = d;
    }
  }
}

// ---------------- last layer: norm + residual (bf16 X) + pooling partials ----------------
__global__ __launch_bounds__(256) void k_norm_res(
    const u16* __restrict__ Fb, const int* __restrict__ batch,
    const float* __restrict__ MM, const float* __restrict__ IS,
    const float* __restrict__ w, const float* __restrict__ b,
    u16* __restrict__ Xb, float* __restrict__ SPp) {
  __shared__ float sS[16][64];
  const int tid = threadIdx.x;
  const long n0 = (long)blockIdx.x * 16;
  const int node = tid >> 4;
  const int c4 = (tid & 15) << 2;
  const long n = n0 + node;
  const int g = batch[n];
  ushort4 fu = *(const ushort4*)(Fb + n * 64 + c4);
  float4 f = make_float4(bf2f(fu.x), bf2f(fu.y), bf2f(fu.z), bf2f(fu.w));
  float4 mm = *(const float4*)(MM + g * 64 + c4);
  float4 is = *(const float4*)(IS + g * 64 + c4);
  float4 wv = *(const float4*)(w + c4);
  float4 bv = *(const float4*)(b + c4);
  float4 y;
  y.x = fmaf(wv.x * (f.x - mm.x), is.x, bv.x);
  y.y = fmaf(wv.y * (f.y - mm.y), is.y, bv.y);
  y.z = fmaf(wv.z * (f.z - mm.z), is.z, bv.z);
  y.w = fmaf(wv.w * (f.w - mm.w), is.w, bv.w);
  ushort4 xo = *(const ushort4*)(Xb + n * 64 + c4);
  y.x += bf2f(xo.x); y.y += bf2f(xo.y); y.z += bf2f(xo.z); y.w += bf2f(xo.w);
  union { u16 s[4]; unsigned long long ll; } pk;
  pk.s[0] = f2bf(y.x); pk.s[1] = f2bf(y.y); pk.s[2] = f2bf(y.z); pk.s[3] = f2bf(y.w);
  *(unsigned long long*)(Xb + n * 64 + c4) = pk.ll;
  *(float4*)&sS[node][c4] = y;
  __syncthreads();
  // pooling partial sums (per-graph runs over the block's 16 nodes)
  if (tid < 64) {
    const int part = blockIdx.x & (MPART - 1);
    int gprev = batch[n0];
    float fs = 0.f;
    #pragma unroll
    for (int w2 = 0; w2 < 16; ++w2) {
      int gw = batch[n0 + w2];
      if (gw != gprev) {
        atomicAdd(&SPp[((size_t)part * N_GRAPHS + gprev) * 64 + tid], fs);
        fs = 0.f; gprev = gw;
      }
      fs += sS[w2][tid];
    }
    atomicAdd(&SPp[((size_t)part * N_GRAPHS + gprev) * 64 + tid], fs);
  }
}

// ---------------- pooled MLP head (one block) ----------------
__global__ __launch_bounds__(512) void k_mlp(
    const float* __restrict__ SPp, const int* __restrict__ gstart, const float* __restrict__ gf,
    const float* __restrict__ W0, const float* __restrict__ b0,
    const float* __restrict__ lw0, const float* __restrict__ lb0,
    const float* __restrict__ Wg, const float* __restrict__ bg,
    const float* __restrict__ lwg, const float* __restrict__ lbg,
    const float* __restrict__ hW, const float* __restrict__ hb,
    float* __restrict__ out) {
  __shared__ float P[16][88];
  __shared__ float Z[16][32];
  const int tid = threadIdx.x;
  for (int i = tid; i < 16 * 88; i += 512) {
    int g = i / 88, c = i - g * 88;
    float v;
    if (c < 64) {
      float s = 0.f;
      for (int b = 0; b < MPART; ++b) s += SPp[((size_t)b * N_GRAPHS + g) * 64 + c];
      float cnt = fmaxf((float)(gstart[g + 1] - gstart[g]), 1.0f);
      v = s / cnt;
    } else {
      v = gf[g * GDIM + (c - 64)];
    }
    P[g][c] = v;
  }
  __syncthreads();
  const int g = tid >> 5, c = tid & 31;
  float acc = b0[c];
  for (int k = 0; k < 88; ++k) acc = fmaf(P[g][k], W0[k * 32 + c], acc);
  float z = ln32(gelu_exact(acc), lw0[c], lb0[c]);
  for (int l = 0; l < LL; ++l) {
    Z[g][c] = z;
    __syncthreads();
    float a2 = bg[l * 32 + c];
    const float* Wl = Wg + l * 32 * 32;
    for (int k = 0; k < 32; ++k) a2 = fmaf(Z[g][k], Wl[k * 32 + c], a2);
    __syncthreads();
    z = ln32(gelu_exact(a2), lwg[l * 32 + c], lbg[l * 32 + c]) + z;
  }
  Z[g][c] = z * hW[c];
  __syncthreads();
  if (c == 0) {
    float s = 0.f;
    for (int k = 0; k < 32; ++k) s += Z[g][k];
    out[g] = s + hb[0];
  }
}

extern "C" void kernel_launch(void* const* d_in, const int* in_sizes, int n_in,
                              void* d_out, int out_size, void* d_ws, size_t ws_size,
                              hipStream_t stream) {
  const float* x   = (const float*)d_in[0];
  const int*   ei  = (const int*)d_in[1];
  const int* batch = (const int*)d_in[2];
  const float* gf  = (const float*)d_in[3];
  const float* W0  = (const float*)d_in[4];
  const float* as0 = (const float*)d_in[5];
  const float* ad0 = (const float*)d_in[6];
  const float* b0  = (const float*)d_in[7];
  const float* gw0 = (const float*)d_in[8];
  const float* gb0 = (const float*)d_in[9];
  const float* gm0 = (const float*)d_in[10];
  const float* Wg  = (const float*)d_in[11];
  const float* asg = (const float*)d_in[12];
  const float* adg = (const float*)d_in[13];
  const float* bg  = (const float*)d_in[14];
  const float* gwg = (const float*)d_in[15];
  const float* gbg = (const float*)d_in[16];
  const float* gmg = (const float*)d_in[17];
  const float* mW0 = (const float*)d_in[18];
  const float* mb0 = (const float*)d_in[19];
  const float* lw0 = (const float*)d_in[20];
  const float* lb0 = (const float*)d_in[21];
  const float* mWg = (const float*)d_in[22];
  const float* mbg = (const float*)d_in[23];
  const float* lwg = (const float*)d_in[24];
  const float* lbg = (const float*)d_in[25];
  const float* hW  = (const float*)d_in[26];
  const float* hb  = (const float*)d_in[27];
  float* out = (float*)d_out;
  const int* src = ei;
  const int* dst = ei + N_EDGES;

  char* p = (char*)d_ws;
  auto alloc = [&](size_t bytes) {
    char* r = p;
    p += (bytes + 255) & ~(size_t)255;
    return (void*)r;
  };
  u16*   Xb  = (u16*)alloc((size_t)N_NODES * 64 * 2);
  u16*   Fb  = (u16*)alloc((size_t)N_NODES * 64 * 2);
  u8*    T8  = (u8*)alloc((size_t)N_NODES * 64);
  float* ES  = (float*)alloc((size_t)N_NODES * 4 * 4);
  float* ED  = (float*)alloc((size_t)N_NODES * 4 * 4);
  int* ssrc  = (int*)alloc((size_t)N_EDGES * 4);
  int* deg   = (int*)alloc((size_t)N_NODES * 4);
  int* off   = (int*)alloc((size_t)(N_NODES + 1) * 4);
  int* cur   = (int*)alloc((size_t)N_NODES * 4);
  int* bsum  = (int*)alloc(4096);
  int* gstart = (int*)alloc((N_GRAPHS + 1) * 4);
  u16* W0s   = (u16*)alloc((size_t)W0S_ELEMS * 2);
  u16* Wgs   = (u16*)alloc((size_t)GL * WGS_ELEMS * 2);
  float* SPp = (float*)alloc((size_t)MPART * N_GRAPHS * 64 * 4);
  float* SQp = (float*)alloc((size_t)MPART * N_GRAPHS * 64 * 4);
  float* MM  = (float*)alloc(N_GRAPHS * 64 * 4);
  float* IS  = (float*)alloc(N_GRAPHS * 64 * 4);
  int* cnt   = (int*)alloc(256);
  (void)ws_size; (void)in_sizes; (void)n_in; (void)out_size;

  const int NB = (N_NODES + 255) / 256;
  hipMemsetAsync(deg, 0, (size_t)N_NODES * 4, stream);
  hipMemsetAsync(SPp, 0, (size_t)MPART * N_GRAPHS * 64 * 4 * 2, stream);  // SPp+SQp contiguous
  hipMemsetAsync(cnt, 0, 256, stream);
  k_count_part<<<2048, 256, 0, stream>>>(dst, deg);
  k_block_sums<<<NB, 256, 0, stream>>>(deg, bsum);
  k_scan_bsums<<<1, 512, 0, stream>>>(bsum, NB, off);
  k_scan_final<<<NB, 256, 0, stream>>>(deg, bsum, off, cur);
  k_scatter_part<<<2048, 256, 0, stream>>>(src, dst, cur, ssrc);
  k_graph_starts<<<1, 32, 0, stream>>>(batch, gstart);
  k_prep_w<<<(W0S_ELEMS + GL * WGS_ELEMS + 255) / 256, 256, 0, stream>>>(W0, Wg, W0s, Wgs);

  const int GG = (N_NODES / 16 + 3) / 4;
  k_gemm0<<<GG, 256, 0, stream>>>(x, W0s, as0, ad0, T8, ES, ED);
  for (int l = 0; l < 1 + GL; ++l) {
    const float* bl  = (l == 0) ? b0  : (bg  + (size_t)(l - 1) * 64);
    const float* gwl = (l == 0) ? gw0 : (gwg + (size_t)(l - 1) * 64);
    const float* gbl = (l == 0) ? gb0 : (gbg + (size_t)(l - 1) * 64);
    const float* gml = (l == 0) ? gm0 : (gmg + (size_t)(l - 1) * 64);
    k_edge_agg<<<EBLK, 256, 0, stream>>>(T8, ES, ED, off, ssrc, bl, batch, gstart, gml,
                                         Fb, SPp, SQp, MM, IS, cnt);
    if (l < GL) {
      k_norm_gemm<<<N_NODES / 16, 256, 0, stream>>>(
          Fb, batch, MM, IS, gwl, gbl,
          Wgs + (size_t)l * WGS_ELEMS, asg + (size_t)l * 64, adg + (size_t)l * 64,
          Xb, (l > 0) ? 1 : 0, T8, ES, ED);
    } else {
      k_norm_res<<<N_NODES / 16, 256, 0, stream>>>(Fb, batch, MM, IS, gwl, gbl, Xb, SPp);
    }
  }

  k_mlp<<<1, 512, 0, stream>>>(SPp, gstart, gf, mW0, mb0, lw0, lb0,
                               mWg, mbg, lwg, lbg, hW, hb, out);
}

// Round 14
// 677.549 us; speedup vs baseline: 8.4035x; 8.4035x over previous
//
#include <hip/hip_runtime.h>
#include <math.h>

#define N_NODES 100000
#define N_EDGES 1200000
#define N_GRAPHS 16
#define CH 64
#define HEADS 4
#define GL 6
#define IN_DIM 261
#define GDIM 24
#define LIN 32
#define LL 3
#define EPSN 1e-5f
#define MPART 64           // moment partial copies
#define RNG (N_NODES / 8)  // 12500 nodes per dst-range
#define EBLK 25000         // edge_agg blocks (= N_NODES/4), 8*3125

typedef unsigned short u16;
typedef unsigned char u8;
typedef __attribute__((ext_vector_type(8))) short bf16x8;
typedef __attribute__((ext_vector_type(4))) float f32x4;

__device__ __forceinline__ u16 f2bf(float f) {
  unsigned u = __float_as_uint(f);
  u = (u + 0x7FFFu + ((u >> 16) & 1u)) >> 16;
  return (u16)u;
}
__device__ __forceinline__ float bf2f(u16 v) {
  return __uint_as_float(((unsigned)v) << 16);
}
// OCP e4m3 via gfx950 HW converts
__device__ __forceinline__ u8 f2fp8(float f) {
  int r = __builtin_amdgcn_cvt_pk_fp8_f32(f, f, 0, false);
  return (u8)(r & 0xff);
}
__device__ __forceinline__ float fp82f(int b) {
  return __builtin_amdgcn_cvt_f32_fp8(b, 0);
}

__device__ __forceinline__ float gelu_exact(float x) {
  return 0.5f * x * (1.0f + erff(x * 0.70710678118654752440f));
}

__device__ __forceinline__ float ln32(float x, float w, float b) {
  float m = x;
  m += __shfl_xor(m, 1); m += __shfl_xor(m, 2); m += __shfl_xor(m, 4);
  m += __shfl_xor(m, 8); m += __shfl_xor(m, 16);
  m *= (1.0f / 32.0f);
  float d = x - m;
  float v = d * d;
  v += __shfl_xor(v, 1); v += __shfl_xor(v, 2); v += __shfl_xor(v, 4);
  v += __shfl_xor(v, 8); v += __shfl_xor(v, 16);
  v *= (1.0f / 32.0f);
  return d * rsqrtf(v + EPSN) * w + b;
}

// ---------------- setup: CSR build, dst-range partitioned ----------------
__global__ void k_count_part(const int* __restrict__ dst, int* __restrict__ deg) {
  const int range = blockIdx.x & 7;
  const int sub = blockIdx.x >> 3;
  const int lo = range * RNG, hi = lo + RNG;
  for (int e = sub * 256 + threadIdx.x; e < N_EDGES; e += 256 * 256) {
    int d = dst[e];
    if (d >= lo && d < hi) atomicAdd(&deg[d], 1);
  }
}

__global__ void k_scatter_part(const int* __restrict__ src, const int* __restrict__ dst,
                               int* __restrict__ cur, int* __restrict__ ssrc) {
  const int range = blockIdx.x & 7;
  const int sub = blockIdx.x >> 3;
  const int lo = range * RNG, hi = lo + RNG;
  for (int e = sub * 256 + threadIdx.x; e < N_EDGES; e += 256 * 256) {
    int d = dst[e];
    if (d >= lo && d < hi) {
      int p = atomicAdd(&cur[d], 1);
      ssrc[p] = src[e];
    }
  }
}

__global__ void k_block_sums(const int* __restrict__ deg, int* __restrict__ bsum) {
  __shared__ int sh[256];
  int i = blockIdx.x * 256 + threadIdx.x;
  sh[threadIdx.x] = (i < N_NODES) ? deg[i] : 0;
  __syncthreads();
  for (int s = 128; s > 0; s >>= 1) {
    if (threadIdx.x < s) sh[threadIdx.x] += sh[threadIdx.x + s];
    __syncthreads();
  }
  if (threadIdx.x == 0) bsum[blockIdx.x] = sh[0];
}

__global__ void k_scan_bsums(int* __restrict__ bsum, int nb, int* __restrict__ off) {
  __shared__ int sh[512];
  int i = threadIdx.x;
  int v = (i < nb) ? bsum[i] : 0;
  sh[i] = v;
  __syncthreads();
  for (int s = 1; s < 512; s <<= 1) {
    int t = (i >= s) ? sh[i - s] : 0;
    __syncthreads();
    sh[i] += t;
    __syncthreads();
  }
  if (i < nb) bsum[i] = sh[i] - v;
  if (i == nb - 1) off[N_NODES] = sh[i];
}

__global__ void k_scan_final(const int* __restrict__ deg, const int* __restrict__ bsum,
                             int* __restrict__ off, int* __restrict__ cur) {
  __shared__ int sh[256];
  int i = blockIdx.x * 256 + threadIdx.x;
  int v = (i < N_NODES) ? deg[i] : 0;
  sh[threadIdx.x] = v;
  __syncthreads();
  for (int s = 1; s < 256; s <<= 1) {
    int t = (threadIdx.x >= s) ? sh[threadIdx.x - s] : 0;
    __syncthreads();
    sh[threadIdx.x] += t;
    __syncthreads();
  }
  if (i < N_NODES) {
    int ex = bsum[blockIdx.x] + sh[threadIdx.x] - v;
    off[i] = ex;
    cur[i] = ex;
  }
}

__global__ void k_graph_starts(const int* __restrict__ batch, int* __restrict__ gstart) {
  int g = threadIdx.x;
  if (g > N_GRAPHS) return;
  int lo = 0, hi = N_NODES;
  while (lo < hi) {
    int mid = (lo + hi) >> 1;
    if (batch[mid] < g) lo = mid + 1; else hi = mid;
  }
  gstart[g] = lo;
}

// ---------------- weight prep: fp32 -> bf16 B-fragment swizzle ----------------
#define W0S_ELEMS (4 * 9 * 64 * 8)
#define WGS_ELEMS (4 * 2 * 64 * 8)
__global__ void k_prep_w(const float* __restrict__ W0, const float* __restrict__ Wg,
                         u16* __restrict__ W0s, u16* __restrict__ Wgs) {
  int idx = blockIdx.x * 256 + threadIdx.x;
  if (idx < W0S_ELEMS) {
    int i = idx & 7, lane = (idx >> 3) & 63, ks = (idx >> 9) % 9, cb = idx / (9 * 512);
    int k = ks * 32 + (lane >> 4) * 8 + i, c = cb * 16 + (lane & 15);
    W0s[idx] = f2bf(k < IN_DIM ? W0[k * 64 + c] : 0.f);
  } else if (idx < W0S_ELEMS + GL * WGS_ELEMS) {
    int j = idx - W0S_ELEMS;
    int l = j / WGS_ELEMS, p = j % WGS_ELEMS;
    int i = p & 7, lane = (p >> 3) & 63, ks = (p >> 9) & 1, cb = p / (2 * 512);
    int k = ks * 32 + (lane >> 4) * 8 + i, c = cb * 16 + (lane & 15);
    Wgs[j] = f2bf(Wg[(size_t)l * 4096 + k * 64 + c]);
  }
}

// ---------------- layer 0: standalone MFMA GEMM + logits (fp8 T out) ----------------
__global__ __launch_bounds__(256) void k_gemm0(
    const float* __restrict__ Xin, const u16* __restrict__ Wswz,
    const float* __restrict__ a_src, const float* __restrict__ a_dst,
    u8* __restrict__ T8, float* __restrict__ ES, float* __restrict__ ED) {
  const int lane = threadIdx.x & 63;
  const int wid = (blockIdx.x << 2) + (threadIdx.x >> 6);
  const int NT = N_NODES / 16;
  if (wid >= NT) return;
  const int grp = lane >> 4, n16 = lane & 15;
  float as_l[4], ad_l[4];
  #pragma unroll
  for (int cb = 0; cb < 4; ++cb) {
    as_l[cb] = a_src[cb * 16 + n16];
    ad_l[cb] = a_dst[cb * 16 + n16];
  }
  const long r0 = (long)wid * 16;

  bf16x8 afr[9];
  const float* xr = Xin + (r0 + n16) * (size_t)IN_DIM;
  #pragma unroll
  for (int ks = 0; ks < 9; ++ks) {
    bf16x8 a;
    #pragma unroll
    for (int i = 0; i < 8; ++i) {
      int k = ks * 32 + grp * 8 + i;
      float v = (k < IN_DIM) ? xr[k] : 0.f;
      a[i] = (short)f2bf(v);
    }
    afr[ks] = a;
  }

  #pragma unroll
  for (int cb = 0; cb < 4; ++cb) {
    f32x4 a = {0.f, 0.f, 0.f, 0.f};
    #pragma unroll
    for (int ks = 0; ks < 9; ++ks) {
      bf16x8 b = *(const bf16x8*)(Wswz + ((size_t)(cb * 9 + ks) * 64 + lane) * 8);
      a = __builtin_amdgcn_mfma_f32_16x16x32_bf16(afr[ks], b, a, 0, 0, 0);
    }
    #pragma unroll
    for (int r = 0; r < 4; ++r) {
      const long row = r0 + grp * 4 + r;
      float v = a[r];
      T8[row * 64 + cb * 16 + n16] = f2fp8(v);
      float s = v * as_l[cb];
      float d = v * ad_l[cb];
      s += __shfl_xor(s, 1); s += __shfl_xor(s, 2); s += __shfl_xor(s, 4); s += __shfl_xor(s, 8);
      d += __shfl_xor(d, 1); d += __shfl_xor(d, 2); d += __shfl_xor(d, 4); d += __shfl_xor(d, 8);
      if (n16 == 0) {
        ES[row * 4 + cb] = s;
        ED[row * 4 + cb] = d;
      }
    }
  }
}

// ---------------- edge softmax + aggregate + LDS-reduced moment partials ----------------
__global__ __launch_bounds__(256) void k_edge_agg(
    const u8* __restrict__ T8, const float* __restrict__ ES, const float* __restrict__ ED,
    const int* __restrict__ off, const int* __restrict__ ssrc,
    const float* __restrict__ bias, const int* __restrict__ batch,
    u16* __restrict__ Fb, float* __restrict__ SPp, float* __restrict__ SQp) {
  __shared__ float sF[4][64];
  __shared__ float sQ[4][64];
  const int lane = threadIdx.x & 63;
  const int wv = threadIdx.x >> 6;
  // XCD-chunked swizzle: 25000 blocks = 8 * 3125
  const int bid = (blockIdx.x & 7) * (EBLK / 8) + (blockIdx.x >> 3);
  const int n = bid * 4 + wv;
  const int e0 = off[n];
  const int ec = off[n + 1] - e0;
  const int hd = lane & 3;
  const int qh = lane >> 4;
  const u8* Tl = T8 + lane;
  const float tself = fp82f(Tl[(long)n * 64]);   // issue early
  const float ed_h = ED[n * 4 + hd];
  float x0 = ES[n * 4 + hd] + ed_h;
  x0 = fmaxf(x0, 0.2f * x0);
  const float p0 = __expf(fminf(x0, 25.f));
  float s_run = p0;
  float acc = __shfl(p0, qh) * tself;
  for (int base = 0; base < ec; base += 16) {
    const int eidx = base + (lane >> 2);
    const bool valid = eidx < ec;
    const int sv = valid ? ssrc[e0 + eidx] : n;
    int rows[16];
    #pragma unroll
    for (int e = 0; e < 16; ++e) rows[e] = __shfl(sv, e << 2);
    int tvb[16];
    #pragma unroll
    for (int e = 0; e < 16; ++e) tvb[e] = Tl[(long)rows[e] * 64];
    float v = ES[sv * 4 + hd] + ed_h;
    v = fmaxf(v, 0.2f * v);
    const float p = valid ? __expf(fminf(v, 25.f)) : 0.f;
    float ps = p;
    ps += __shfl_xor(ps, 4); ps += __shfl_xor(ps, 8);
    ps += __shfl_xor(ps, 16); ps += __shfl_xor(ps, 32);
    s_run += ps;
    #pragma unroll
    for (int e = 0; e < 16; ++e)
      acc = fmaf(__shfl(p, (e << 2) | qh), fp82f(tvb[e]), acc);
  }
  const float s_q = __shfl(s_run, qh);
  const float o = acc / (s_q + 1e-16f) + bias[lane];
  const float f = gelu_exact(o);
  Fb[(long)n * 64 + lane] = f2bf(f);
  sF[wv][lane] = f;
  sQ[wv][lane] = f * f;
  __syncthreads();
  // per-block LDS reduce, one atomic pair per graph-run (typically 1 run)
  if (threadIdx.x < 64) {
    const int part = bid & (MPART - 1);
    const long nb = (long)bid * 4;
    int gprev = batch[nb];
    float fs = 0.f, qs = 0.f;
    #pragma unroll
    for (int w2 = 0; w2 < 4; ++w2) {
      int gw = batch[nb + w2];
      if (gw != gprev) {
        atomicAdd(&SPp[((size_t)part * N_GRAPHS + gprev) * 64 + threadIdx.x], fs);
        atomicAdd(&SQp[((size_t)part * N_GRAPHS + gprev) * 64 + threadIdx.x], qs);
        fs = 0.f; qs = 0.f; gprev = gw;
      }
      fs += sF[w2][threadIdx.x];
      qs += sQ[w2][threadIdx.x];
    }
    atomicAdd(&SPp[((size_t)part * N_GRAPHS + gprev) * 64 + threadIdx.x], fs);
    atomicAdd(&SQp[((size_t)part * N_GRAPHS + gprev) * 64 + threadIdx.x], qs);
  }
}

// ---------------- per-layer stats: reduce partials -> MM/IS, re-zero ----------------
__global__ void k_stats(const int* __restrict__ gstart, const float* __restrict__ ms,
                        float* __restrict__ SPp, float* __restrict__ SQp,
                        float* __restrict__ MM, float* __restrict__ IS) {
  const int g = blockIdx.x;
  const int t = threadIdx.x;         // 256
  const int c = t & 63, chunk = t >> 6;
  float s = 0.f, q = 0.f;
  for (int p2 = chunk * 16; p2 < chunk * 16 + 16; ++p2) {
    size_t i = ((size_t)p2 * N_GRAPHS + g) * 64 + c;
    s += SPp[i]; SPp[i] = 0.f;
    q += SQp[i]; SQp[i] = 0.f;
  }
  __shared__ float ls[4][64];
  __shared__ float lq[4][64];
  ls[chunk][c] = s;
  lq[chunk][c] = q;
  __syncthreads();
  if (t < 64) {
    s = ls[0][t] + ls[1][t] + ls[2][t] + ls[3][t];
    q = lq[0][t] + lq[1][t] + lq[2][t] + lq[3][t];
    float cnt = fmaxf((float)(gstart[g + 1] - gstart[g]), 1.0f);
    float mean = s / cnt;
    float mm = mean * ms[t];
    float var = q / cnt - 2.f * mm * mean + mm * mm;
    MM[g * 64 + t] = mm;
    IS[g * 64 + t] = rsqrtf(fmaxf(var, 0.f) + EPSN);
  }
}

// ---------------- fused: GraphNorm + residual (bf16 X) + NEXT layer's GEMM + logits ----------------
__global__ __launch_bounds__(256) void k_norm_gemm(
    const u16* __restrict__ Fb, const int* __restrict__ batch,
    const float* __restrict__ MM, const float* __restrict__ IS,
    const float* __restrict__ w, const float* __restrict__ b,
    const u16* __restrict__ Wswz, const float* __restrict__ a_src,
    const float* __restrict__ a_dst, u16* __restrict__ Xb, int residual,
    u8* __restrict__ T8, float* __restrict__ ES, float* __restrict__ ED) {
  __shared__ __align__(16) u16 sY[16][72];   // 144B rows: 16B-aligned
  const int tid = threadIdx.x;
  const long n0 = (long)blockIdx.x * 16;
  {
    const int node = tid >> 4;
    const int c4 = (tid & 15) << 2;
    const long n = n0 + node;
    const int g = batch[n];
    ushort4 fu = *(const ushort4*)(Fb + n * 64 + c4);
    float4 f = make_float4(bf2f(fu.x), bf2f(fu.y), bf2f(fu.z), bf2f(fu.w));
    float4 mm = *(const float4*)(MM + g * 64 + c4);
    float4 is = *(const float4*)(IS + g * 64 + c4);
    float4 wv = *(const float4*)(w + c4);
    float4 bv = *(const float4*)(b + c4);
    float4 y;
    y.x = fmaf(wv.x * (f.x - mm.x), is.x, bv.x);
    y.y = fmaf(wv.y * (f.y - mm.y), is.y, bv.y);
    y.z = fmaf(wv.z * (f.z - mm.z), is.z, bv.z);
    y.w = fmaf(wv.w * (f.w - mm.w), is.w, bv.w);
    if (residual) {
      ushort4 xo = *(const ushort4*)(Xb + n * 64 + c4);
      y.x += bf2f(xo.x); y.y += bf2f(xo.y); y.z += bf2f(xo.z); y.w += bf2f(xo.w);
    }
    union { u16 s[4]; unsigned long long ll; } pk;
    pk.s[0] = f2bf(y.x); pk.s[1] = f2bf(y.y); pk.s[2] = f2bf(y.z); pk.s[3] = f2bf(y.w);
    *(unsigned long long*)(Xb + n * 64 + c4) = pk.ll;
    *(unsigned long long*)&sY[node][c4] = pk.ll;
  }
  __syncthreads();
  const int lane = tid & 63;
  const int wid = tid >> 6;
  const int grp = lane >> 4, n16 = lane & 15;
  bf16x8 afr[2];
  #pragma unroll
  for (int ks = 0; ks < 2; ++ks)
    afr[ks] = *(const bf16x8*)(&sY[n16][ks * 32 + grp * 8]);
  f32x4 a = {0.f, 0.f, 0.f, 0.f};
  #pragma unroll
  for (int ks = 0; ks < 2; ++ks) {
    bf16x8 bb = *(const bf16x8*)(Wswz + ((size_t)(wid * 2 + ks) * 64 + lane) * 8);
    a = __builtin_amdgcn_mfma_f32_16x16x32_bf16(afr[ks], bb, a, 0, 0, 0);
  }
  const float as_c = a_src[wid * 16 + n16];
  const float ad_c = a_dst[wid * 16 + n16];
  #pragma unroll
  for (int r = 0; r < 4; ++r) {
    const long row = n0 + grp * 4 + r;
    float v = a[r];
    T8[row * 64 + wid * 16 + n16] = f2fp8(v);
    float s = v * as_c;
    float d = v * ad_c;
    s += __shfl_xor(s, 1); s += __shfl_xor(s, 2); s += __shfl_xor(s, 4); s += __shfl_xor(s, 8);
    d += __shfl_xor(d, 1); d += __shfl_xor(d, 2); d += __shfl_xor(d, 4); d += __shfl_xor(d, 8);
    if (n16 == 0) {
      ES[row * 4 + wid] = s;
      ED[row * 4 + wid] = d;
    }
  }
}

// ---------------- last layer: norm + residual (bf16 X) + pooling partials ----------------
__global__ __launch_bounds__(256) void k_norm_res(
    const u16* __restrict__ Fb, const int* __restrict__ batch,
    const float* __restrict__ MM, const float* __restrict__ IS,
    const float* __restrict__ w, const float* __restrict__ b,
    u16* __restrict__ Xb, float* __restrict__ SPp) {
  __shared__ float sS[16][64];
  const int tid = threadIdx.x;
  const long n0 = (long)blockIdx.x * 16;
  const int node = tid >> 4;
  const int c4 = (tid & 15) << 2;
  const long n = n0 + node;
  const int g = batch[n];
  ushort4 fu = *(const ushort4*)(Fb + n * 64 + c4);
  float4 f = make_float4(bf2f(fu.x), bf2f(fu.y), bf2f(fu.z), bf2f(fu.w));
  float4 mm = *(const float4*)(MM + g * 64 + c4);
  float4 is = *(const float4*)(IS + g * 64 + c4);
  float4 wv = *(const float4*)(w + c4);
  float4 bv = *(const float4*)(b + c4);
  float4 y;
  y.x = fmaf(wv.x * (f.x - mm.x), is.x, bv.x);
  y.y = fmaf(wv.y * (f.y - mm.y), is.y, bv.y);
  y.z = fmaf(wv.z * (f.z - mm.z), is.z, bv.z);
  y.w = fmaf(wv.w * (f.w - mm.w), is.w, bv.w);
  ushort4 xo = *(const ushort4*)(Xb + n * 64 + c4);
  y.x += bf2f(xo.x); y.y += bf2f(xo.y); y.z += bf2f(xo.z); y.w += bf2f(xo.w);
  *(float4*)&sS[node][c4] = y;
  __syncthreads();
  // pooling partial sums (per-graph runs over the block's 16 nodes)
  if (tid < 64) {
    const int part = blockIdx.x & (MPART - 1);
    int gprev = batch[n0];
    float fs = 0.f;
    #pragma unroll
    for (int w2 = 0; w2 < 16; ++w2) {
      int gw = batch[n0 + w2];
      if (gw != gprev) {
        atomicAdd(&SPp[((size_t)part * N_GRAPHS + gprev) * 64 + tid], fs);
        fs = 0.f; gprev = gw;
      }
      fs += sS[w2][tid];
    }
    atomicAdd(&SPp[((size_t)part * N_GRAPHS + gprev) * 64 + tid], fs);
  }
}

// ---------------- pooled MLP head (one block) ----------------
__global__ __launch_bounds__(512) void k_mlp(
    const float* __restrict__ SPp, const int* __restrict__ gstart, const float* __restrict__ gf,
    const float* __restrict__ W0, const float* __restrict__ b0,
    const float* __restrict__ lw0, const float* __restrict__ lb0,
    const float* __restrict__ Wg, const float* __restrict__ bg,
    const float* __restrict__ lwg, const float* __restrict__ lbg,
    const float* __restrict__ hW, const float* __restrict__ hb,
    float* __restrict__ out) {
  __shared__ float P[16][88];
  __shared__ float Z[16][32];
  const int tid = threadIdx.x;
  for (int i = tid; i < 16 * 88; i += 512) {
    int g = i / 88, c = i - g * 88;
    float v;
    if (c < 64) {
      float s = 0.f;
      for (int b = 0; b < MPART; ++b) s += SPp[((size_t)b * N_GRAPHS + g) * 64 + c];
      float cnt = fmaxf((float)(gstart[g + 1] - gstart[g]), 1.0f);
      v = s / cnt;
    } else {
      v = gf[g * GDIM + (c - 64)];
    }
    P[g][c] = v;
  }
  __syncthreads();
  const int g = tid >> 5, c = tid & 31;
  float acc = b0[c];
  for (int k = 0; k < 88; ++k) acc = fmaf(P[g][k], W0[k * 32 + c], acc);
  float z = ln32(gelu_exact(acc), lw0[c], lb0[c]);
  for (int l = 0; l < LL; ++l) {
    Z[g][c] = z;
    __syncthreads();
    float a2 = bg[l * 32 + c];
    const float* Wl = Wg + l * 32 * 32;
    for (int k = 0; k < 32; ++k) a2 = fmaf(Z[g][k], Wl[k * 32 + c], a2);
    __syncthreads();
    z = ln32(gelu_exact(a2), lwg[l * 32 + c], lbg[l * 32 + c]) + z;
  }
  Z[g][c] = z * hW[c];
  __syncthreads();
  if (c == 0) {
    float s = 0.f;
    for (int k = 0; k < 32; ++k) s += Z[g][k];
    out[g] = s + hb[0];
  }
}

extern "C" void kernel_launch(void* const* d_in, const int* in_sizes, int n_in,
                              void* d_out, int out_size, void* d_ws, size_t ws_size,
                              hipStream_t stream) {
  const float* x   = (const float*)d_in[0];
  const int*   ei  = (const int*)d_in[1];
  const int* batch = (const int*)d_in[2];
  const float* gf  = (const float*)d_in[3];
  const float* W0  = (const float*)d_in[4];
  const float* as0 = (const float*)d_in[5];
  const float* ad0 = (const float*)d_in[6];
  const float* b0  = (const float*)d_in[7];
  const float* gw0 = (const float*)d_in[8];
  const float* gb0 = (const float*)d_in[9];
  const float* gm0 = (const float*)d_in[10];
  const float* Wg  = (const float*)d_in[11];
  const float* asg = (const float*)d_in[12];
  const float* adg = (const float*)d_in[13];
  const float* bg  = (const float*)d_in[14];
  const float* gwg = (const float*)d_in[15];
  const float* gbg = (const float*)d_in[16];
  const float* gmg = (const float*)d_in[17];
  const float* mW0 = (const float*)d_in[18];
  const float* mb0 = (const float*)d_in[19];
  const float* lw0 = (const float*)d_in[20];
  const float* lb0 = (const float*)d_in[21];
  const float* mWg = (const float*)d_in[22];
  const float* mbg = (const float*)d_in[23];
  const float* lwg = (const float*)d_in[24];
  const float* lbg = (const float*)d_in[25];
  const float* hW  = (const float*)d_in[26];
  const float* hb  = (const float*)d_in[27];
  float* out = (float*)d_out;
  const int* src = ei;
  const int* dst = ei + N_EDGES;

  char* p = (char*)d_ws;
  auto alloc = [&](size_t bytes) {
    char* r = p;
    p += (bytes + 255) & ~(size_t)255;
    return (void*)r;
  };
  u16*   Xb  = (u16*)alloc((size_t)N_NODES * 64 * 2);
  u16*   Fb  = (u16*)alloc((size_t)N_NODES * 64 * 2);
  u8*    T8  = (u8*)alloc((size_t)N_NODES * 64);
  float* ES  = (float*)alloc((size_t)N_NODES * 4 * 4);
  float* ED  = (float*)alloc((size_t)N_NODES * 4 * 4);
  int* ssrc  = (int*)alloc((size_t)N_EDGES * 4);
  int* deg   = (int*)alloc((size_t)N_NODES * 4);
  int* off   = (int*)alloc((size_t)(N_NODES + 1) * 4);
  int* cur   = (int*)alloc((size_t)N_NODES * 4);
  int* bsum  = (int*)alloc(4096);
  int* gstart = (int*)alloc((N_GRAPHS + 1) * 4);
  u16* W0s   = (u16*)alloc((size_t)W0S_ELEMS * 2);
  u16* Wgs   = (u16*)alloc((size_t)GL * WGS_ELEMS * 2);
  float* SPp = (float*)alloc((size_t)MPART * N_GRAPHS * 64 * 4);
  float* SQp = (float*)alloc((size_t)MPART * N_GRAPHS * 64 * 4);
  float* MM  = (float*)alloc(N_GRAPHS * 64 * 4);
  float* IS  = (float*)alloc(N_GRAPHS * 64 * 4);
  (void)ws_size; (void)in_sizes; (void)n_in; (void)out_size;

  const int NB = (N_NODES + 255) / 256;
  hipMemsetAsync(deg, 0, (size_t)N_NODES * 4, stream);
  hipMemsetAsync(SPp, 0, (size_t)MPART * N_GRAPHS * 64 * 4 * 2, stream);  // SPp+SQp contiguous
  k_count_part<<<2048, 256, 0, stream>>>(dst, deg);
  k_block_sums<<<NB, 256, 0, stream>>>(deg, bsum);
  k_scan_bsums<<<1, 512, 0, stream>>>(bsum, NB, off);
  k_scan_final<<<NB, 256, 0, stream>>>(deg, bsum, off, cur);
  k_scatter_part<<<2048, 256, 0, stream>>>(src, dst, cur, ssrc);
  k_graph_starts<<<1, 32, 0, stream>>>(batch, gstart);
  k_prep_w<<<(W0S_ELEMS + GL * WGS_ELEMS + 255) / 256, 256, 0, stream>>>(W0, Wg, W0s, Wgs);

  const int GG = (N_NODES / 16 + 3) / 4;
  k_gemm0<<<GG, 256, 0, stream>>>(x, W0s, as0, ad0, T8, ES, ED);
  for (int l = 0; l < 1 + GL; ++l) {
    const float* bl  = (l == 0) ? b0  : (bg  + (size_t)(l - 1) * 64);
    const float* gwl = (l == 0) ? gw0 : (gwg + (size_t)(l - 1) * 64);
    const float* gbl = (l == 0) ? gb0 : (gbg + (size_t)(l - 1) * 64);
    const float* gml = (l == 0) ? gm0 : (gmg + (size_t)(l - 1) * 64);
    k_edge_agg<<<EBLK, 256, 0, stream>>>(T8, ES, ED, off, ssrc, bl, batch, Fb, SPp, SQp);
    k_stats<<<N_GRAPHS, 256, 0, stream>>>(gstart, gml, SPp, SQp, MM, IS);
    if (l < GL) {
      k_norm_gemm<<<N_NODES / 16, 256, 0, stream>>>(
          Fb, batch, MM, IS, gwl, gbl,
          Wgs + (size_t)l * WGS_ELEMS, asg + (size_t)l * 64, adg + (size_t)l * 64,
          Xb, (l > 0) ? 1 : 0, T8, ES, ED);
    } else {
      k_norm_res<<<N_NODES / 16, 256, 0, stream>>>(Fb, batch, MM, IS, gwl, gbl, Xb, SPp);
    }
  }

  k_mlp<<<1, 512, 0, stream>>>(SPp, gstart, gf, mW0, mb0, lw0, lb0,
                               mWg, mbg, lwg, lbg, hW, hb, out);
}

// Round 16
// 624.864 us; speedup vs baseline: 9.1120x; 1.0843x over previous
//
#include <hip/hip_runtime.h>
#include <math.h>

#define N_NODES 100000
#define N_EDGES 1200000
#define N_GRAPHS 16
#define CH 64
#define HEADS 4
#define GL 6
#define IN_DIM 261
#define GDIM 24
#define LIN 32
#define LL 3
#define EPSN 1e-5f
#define MPART 64           // moment partial copies
#define RNG (N_NODES / 8)  // 12500 nodes per dst-range
#define EBLK 25000         // edge_agg blocks (= N_NODES/4), 8*3125

typedef unsigned short u16;
typedef unsigned char u8;
typedef unsigned int u32;
typedef __attribute__((ext_vector_type(8))) short bf16x8;
typedef __attribute__((ext_vector_type(4))) float f32x4;

__device__ __forceinline__ u16 f2bf(float f) {
  unsigned u = __float_as_uint(f);
  u = (u + 0x7FFFu + ((u >> 16) & 1u)) >> 16;
  return (u16)u;
}
__device__ __forceinline__ float bf2f(u16 v) {
  return __uint_as_float(((unsigned)v) << 16);
}
// OCP e4m3 via gfx950 HW converts
__device__ __forceinline__ u8 f2fp8(float f) {
  int r = __builtin_amdgcn_cvt_pk_fp8_f32(f, f, 0, false);
  return (u8)(r & 0xff);
}

__device__ __forceinline__ float gelu_exact(float x) {
  return 0.5f * x * (1.0f + erff(x * 0.70710678118654752440f));
}

__device__ __forceinline__ float ln32(float x, float w, float b) {
  float m = x;
  m += __shfl_xor(m, 1); m += __shfl_xor(m, 2); m += __shfl_xor(m, 4);
  m += __shfl_xor(m, 8); m += __shfl_xor(m, 16);
  m *= (1.0f / 32.0f);
  float d = x - m;
  float v = d * d;
  v += __shfl_xor(v, 1); v += __shfl_xor(v, 2); v += __shfl_xor(v, 4);
  v += __shfl_xor(v, 8); v += __shfl_xor(v, 16);
  v *= (1.0f / 32.0f);
  return d * rsqrtf(v + EPSN) * w + b;
}

// ---------------- setup: CSR build, dst-range partitioned ----------------
__global__ void k_count_part(const int* __restrict__ dst, int* __restrict__ deg) {
  const int range = blockIdx.x & 7;
  const int sub = blockIdx.x >> 3;
  const int lo = range * RNG, hi = lo + RNG;
  for (int e = sub * 256 + threadIdx.x; e < N_EDGES; e += 256 * 256) {
    int d = dst[e];
    if (d >= lo && d < hi) atomicAdd(&deg[d], 1);
  }
}

__global__ void k_scatter_part(const int* __restrict__ src, const int* __restrict__ dst,
                               int* __restrict__ cur, int* __restrict__ ssrc) {
  const int range = blockIdx.x & 7;
  const int sub = blockIdx.x >> 3;
  const int lo = range * RNG, hi = lo + RNG;
  for (int e = sub * 256 + threadIdx.x; e < N_EDGES; e += 256 * 256) {
    int d = dst[e];
    if (d >= lo && d < hi) {
      int p = atomicAdd(&cur[d], 1);
      ssrc[p] = src[e];
    }
  }
}

__global__ void k_block_sums(const int* __restrict__ deg, int* __restrict__ bsum) {
  __shared__ int sh[256];
  int i = blockIdx.x * 256 + threadIdx.x;
  sh[threadIdx.x] = (i < N_NODES) ? deg[i] : 0;
  __syncthreads();
  for (int s = 128; s > 0; s >>= 1) {
    if (threadIdx.x < s) sh[threadIdx.x] += sh[threadIdx.x + s];
    __syncthreads();
  }
  if (threadIdx.x == 0) bsum[blockIdx.x] = sh[0];
}

__global__ void k_scan_bsums(int* __restrict__ bsum, int nb, int* __restrict__ off) {
  __shared__ int sh[512];
  int i = threadIdx.x;
  int v = (i < nb) ? bsum[i] : 0;
  sh[i] = v;
  __syncthreads();
  for (int s = 1; s < 512; s <<= 1) {
    int t = (i >= s) ? sh[i - s] : 0;
    __syncthreads();
    sh[i] += t;
    __syncthreads();
  }
  if (i < nb) bsum[i] = sh[i] - v;
  if (i == nb - 1) off[N_NODES] = sh[i];
}

__global__ void k_scan_final(const int* __restrict__ deg, const int* __restrict__ bsum,
                             int* __restrict__ off, int* __restrict__ cur) {
  __shared__ int sh[256];
  int i = blockIdx.x * 256 + threadIdx.x;
  int v = (i < N_NODES) ? deg[i] : 0;
  sh[threadIdx.x] = v;
  __syncthreads();
  for (int s = 1; s < 256; s <<= 1) {
    int t = (threadIdx.x >= s) ? sh[threadIdx.x - s] : 0;
    __syncthreads();
    sh[threadIdx.x] += t;
    __syncthreads();
  }
  if (i < N_NODES) {
    int ex = bsum[blockIdx.x] + sh[threadIdx.x] - v;
    off[i] = ex;
    cur[i] = ex;
  }
}

__global__ void k_graph_starts(const int* __restrict__ batch, int* __restrict__ gstart) {
  int g = threadIdx.x;
  if (g > N_GRAPHS) return;
  int lo = 0, hi = N_NODES;
  while (lo < hi) {
    int mid = (lo + hi) >> 1;
    if (batch[mid] < g) lo = mid + 1; else hi = mid;
  }
  gstart[g] = lo;
}

// ---------------- weight prep: fp32 -> bf16 B-fragment swizzle ----------------
#define W0S_ELEMS (4 * 9 * 64 * 8)
#define WGS_ELEMS (4 * 2 * 64 * 8)
__global__ void k_prep_w(const float* __restrict__ W0, const float* __restrict__ Wg,
                         u16* __restrict__ W0s, u16* __restrict__ Wgs) {
  int idx = blockIdx.x * 256 + threadIdx.x;
  if (idx < W0S_ELEMS) {
    int i = idx & 7, lane = (idx >> 3) & 63, ks = (idx >> 9) % 9, cb = idx / (9 * 512);
    int k = ks * 32 + (lane >> 4) * 8 + i, c = cb * 16 + (lane & 15);
    W0s[idx] = f2bf(k < IN_DIM ? W0[k * 64 + c] : 0.f);
  } else if (idx < W0S_ELEMS + GL * WGS_ELEMS) {
    int j = idx - W0S_ELEMS;
    int l = j / WGS_ELEMS, p = j % WGS_ELEMS;
    int i = p & 7, lane = (p >> 3) & 63, ks = (p >> 9) & 1, cb = p / (2 * 512);
    int k = ks * 32 + (lane >> 4) * 8 + i, c = cb * 16 + (lane & 15);
    Wgs[j] = f2bf(Wg[(size_t)l * 4096 + k * 64 + c]);
  }
}

// ---------------- layer 0: standalone MFMA GEMM + logits (fp8 T out) ----------------
__global__ __launch_bounds__(256) void k_gemm0(
    const float* __restrict__ Xin, const u16* __restrict__ Wswz,
    const float* __restrict__ a_src, const float* __restrict__ a_dst,
    u8* __restrict__ T8, float* __restrict__ ES, float* __restrict__ ED) {
  const int lane = threadIdx.x & 63;
  const int wid = (blockIdx.x << 2) + (threadIdx.x >> 6);
  const int NT = N_NODES / 16;
  if (wid >= NT) return;
  const int grp = lane >> 4, n16 = lane & 15;
  float as_l[4], ad_l[4];
  #pragma unroll
  for (int cb = 0; cb < 4; ++cb) {
    as_l[cb] = a_src[cb * 16 + n16];
    ad_l[cb] = a_dst[cb * 16 + n16];
  }
  const long r0 = (long)wid * 16;

  bf16x8 afr[9];
  const float* xr = Xin + (r0 + n16) * (size_t)IN_DIM;
  #pragma unroll
  for (int ks = 0; ks < 9; ++ks) {
    bf16x8 a;
    #pragma unroll
    for (int i = 0; i < 8; ++i) {
      int k = ks * 32 + grp * 8 + i;
      float v = (k < IN_DIM) ? xr[k] : 0.f;
      a[i] = (short)f2bf(v);
    }
    afr[ks] = a;
  }

  #pragma unroll
  for (int cb = 0; cb < 4; ++cb) {
    f32x4 a = {0.f, 0.f, 0.f, 0.f};
    #pragma unroll
    for (int ks = 0; ks < 9; ++ks) {
      bf16x8 b = *(const bf16x8*)(Wswz + ((size_t)(cb * 9 + ks) * 64 + lane) * 8);
      a = __builtin_amdgcn_mfma_f32_16x16x32_bf16(afr[ks], b, a, 0, 0, 0);
    }
    #pragma unroll
    for (int r = 0; r < 4; ++r) {
      const long row = r0 + grp * 4 + r;
      float v = a[r];
      T8[row * 64 + cb * 16 + n16] = f2fp8(v);
      float s = v * as_l[cb];
      float d = v * ad_l[cb];
      s += __shfl_xor(s, 1); s += __shfl_xor(s, 2); s += __shfl_xor(s, 4); s += __shfl_xor(s, 8);
      d += __shfl_xor(d, 1); d += __shfl_xor(d, 2); d += __shfl_xor(d, 4); d += __shfl_xor(d, 8);
      if (n16 == 0) {
        ES[row * 4 + cb] = s;
        ED[row * 4 + cb] = d;
      }
    }
  }
}

// ---------------- edge softmax + aggregate (dword gathers) + moment partials ----------------
// Softmax phase: lane = edge(16)*4 + head. Aggregate phase: lane = sub(4 edges) x cg(16
// channel-groups); each lane loads one dword (4 fp8) per edge -> 4x fewer VMEM/addr/bperm ops.
__global__ __launch_bounds__(256) void k_edge_agg(
    const u8* __restrict__ T8, const float* __restrict__ ES, const float* __restrict__ ED,
    const int* __restrict__ off, const int* __restrict__ ssrc,
    const float* __restrict__ bias, const int* __restrict__ batch,
    u16* __restrict__ Fb, float* __restrict__ SPp, float* __restrict__ SQp) {
  __shared__ float sF[4][64];
  __shared__ float sQ[4][64];
  const int lane = threadIdx.x & 63;
  const int wv = threadIdx.x >> 6;
  // XCD-chunked swizzle: 25000 blocks = 8 * 3125
  const int bid = (blockIdx.x & 7) * (EBLK / 8) + (blockIdx.x >> 3);
  const int n = bid * 4 + wv;
  const int e0 = off[n];
  const int ec = off[n + 1] - e0;
  const int hd = lane & 3;     // softmax-phase head
  const int cg = lane & 15;    // aggregate-phase channel group (channels cg*4..+3)
  const int sub = lane >> 4;   // aggregate-phase edge slot
  const int hh = cg >> 2;      // head of my channel group
  const float ed_h = ED[n * 4 + hd];
  float x0 = ES[n * 4 + hd] + ed_h;
  x0 = fmaxf(x0, 0.2f * x0);
  const float p0 = __expf(fminf(x0, 25.f));
  float s_run = p0;
  // self term (counted once: sub==0 only; sub-reduce at the end sums partials)
  const u32 selfw = *(const u32*)(T8 + (size_t)n * 64 + cg * 4);
  const float p0b = __shfl(p0, hh);
  const float selfm = (sub == 0) ? p0b : 0.f;
  float acc4[4];
  acc4[0] = selfm * __builtin_amdgcn_cvt_f32_fp8(selfw, 0);
  acc4[1] = selfm * __builtin_amdgcn_cvt_f32_fp8(selfw, 1);
  acc4[2] = selfm * __builtin_amdgcn_cvt_f32_fp8(selfw, 2);
  acc4[3] = selfm * __builtin_amdgcn_cvt_f32_fp8(selfw, 3);

  for (int base = 0; base < ec; base += 16) {
    const int eidx = base + (lane >> 2);
    const bool valid = eidx < ec;
    const int sv = valid ? ssrc[e0 + eidx] : n;
    // issue the 4 dword gathers first (overlap with ES gather + exp chain)
    int srows[4];
    #pragma unroll
    for (int ps2 = 0; ps2 < 4; ++ps2) srows[ps2] = __shfl(sv, (ps2 * 4 + sub) << 2);
    u32 tw[4];
    #pragma unroll
    for (int ps2 = 0; ps2 < 4; ++ps2)
      tw[ps2] = *(const u32*)(T8 + (size_t)srows[ps2] * 64 + cg * 4);
    // softmax weights
    float v = ES[sv * 4 + hd] + ed_h;
    v = fmaxf(v, 0.2f * v);
    const float p = valid ? __expf(fminf(v, 25.f)) : 0.f;
    float ps = p;
    ps += __shfl_xor(ps, 4); ps += __shfl_xor(ps, 8);
    ps += __shfl_xor(ps, 16); ps += __shfl_xor(ps, 32);
    s_run += ps;
    // accumulate 4 edges x 4 channels per lane
    #pragma unroll
    for (int ps2 = 0; ps2 < 4; ++ps2) {
      const float pe = __shfl(p, (((ps2 * 4 + sub) << 2) | hh));
      acc4[0] = fmaf(pe, __builtin_amdgcn_cvt_f32_fp8(tw[ps2], 0), acc4[0]);
      acc4[1] = fmaf(pe, __builtin_amdgcn_cvt_f32_fp8(tw[ps2], 1), acc4[1]);
      acc4[2] = fmaf(pe, __builtin_amdgcn_cvt_f32_fp8(tw[ps2], 2), acc4[2]);
      acc4[3] = fmaf(pe, __builtin_amdgcn_cvt_f32_fp8(tw[ps2], 3), acc4[3]);
    }
  }
  // reduce over edge slots
  #pragma unroll
  for (int j = 0; j < 4; ++j) {
    acc4[j] += __shfl_xor(acc4[j], 16);
    acc4[j] += __shfl_xor(acc4[j], 32);
  }
  const float s_q = __shfl(s_run, hh);
  const float inv = 1.0f / (s_q + 1e-16f);
  if (sub == 0) {
    const float4 b4 = *(const float4*)(bias + cg * 4);
    float f0 = gelu_exact(fmaf(acc4[0], inv, b4.x));
    float f1 = gelu_exact(fmaf(acc4[1], inv, b4.y));
    float f2 = gelu_exact(fmaf(acc4[2], inv, b4.z));
    float f3 = gelu_exact(fmaf(acc4[3], inv, b4.w));
    union { u16 s[4]; unsigned long long ll; } pk;
    pk.s[0] = f2bf(f0); pk.s[1] = f2bf(f1); pk.s[2] = f2bf(f2); pk.s[3] = f2bf(f3);
    *(unsigned long long*)(Fb + (size_t)n * 64 + cg * 4) = pk.ll;
    sF[wv][cg * 4 + 0] = f0; sQ[wv][cg * 4 + 0] = f0 * f0;
    sF[wv][cg * 4 + 1] = f1; sQ[wv][cg * 4 + 1] = f1 * f1;
    sF[wv][cg * 4 + 2] = f2; sQ[wv][cg * 4 + 2] = f2 * f2;
    sF[wv][cg * 4 + 3] = f3; sQ[wv][cg * 4 + 3] = f3 * f3;
  }
  __syncthreads();
  // per-block LDS reduce, one atomic pair per graph-run (typically 1 run)
  if (threadIdx.x < 64) {
    const int part = bid & (MPART - 1);
    const long nb = (long)bid * 4;
    int gprev = batch[nb];
    float fs = 0.f, qs = 0.f;
    #pragma unroll
    for (int w2 = 0; w2 < 4; ++w2) {
      int gw = batch[nb + w2];
      if (gw != gprev) {
        atomicAdd(&SPp[((size_t)part * N_GRAPHS + gprev) * 64 + threadIdx.x], fs);
        atomicAdd(&SQp[((size_t)part * N_GRAPHS + gprev) * 64 + threadIdx.x], qs);
        fs = 0.f; qs = 0.f; gprev = gw;
      }
      fs += sF[w2][threadIdx.x];
      qs += sQ[w2][threadIdx.x];
    }
    atomicAdd(&SPp[((size_t)part * N_GRAPHS + gprev) * 64 + threadIdx.x], fs);
    atomicAdd(&SQp[((size_t)part * N_GRAPHS + gprev) * 64 + threadIdx.x], qs);
  }
}

// ---------------- per-layer stats: reduce partials -> MM/IS, re-zero ----------------
__global__ void k_stats(const int* __restrict__ gstart, const float* __restrict__ ms,
                        float* __restrict__ SPp, float* __restrict__ SQp,
                        float* __restrict__ MM, float* __restrict__ IS) {
  const int g = blockIdx.x;
  const int t = threadIdx.x;         // 256
  const int c = t & 63, chunk = t >> 6;
  float s = 0.f, q = 0.f;
  for (int p2 = chunk * 16; p2 < chunk * 16 + 16; ++p2) {
    size_t i = ((size_t)p2 * N_GRAPHS + g) * 64 + c;
    s += SPp[i]; SPp[i] = 0.f;
    q += SQp[i]; SQp[i] = 0.f;
  }
  __shared__ float ls[4][64];
  __shared__ float lq[4][64];
  ls[chunk][c] = s;
  lq[chunk][c] = q;
  __syncthreads();
  if (t < 64) {
    s = ls[0][t] + ls[1][t] + ls[2][t] + ls[3][t];
    q = lq[0][t] + lq[1][t] + lq[2][t] + lq[3][t];
    float cnt = fmaxf((float)(gstart[g + 1] - gstart[g]), 1.0f);
    float mean = s / cnt;
    float mm = mean * ms[t];
    float var = q / cnt - 2.f * mm * mean + mm * mm;
    MM[g * 64 + t] = mm;
    IS[g * 64 + t] = rsqrtf(fmaxf(var, 0.f) + EPSN);
  }
}

// ---------------- fused: GraphNorm + residual (bf16 X) + NEXT layer's GEMM + logits ----------------
__global__ __launch_bounds__(256) void k_norm_gemm(
    const u16* __restrict__ Fb, const int* __restrict__ batch,
    const float* __restrict__ MM, const float* __restrict__ IS,
    const float* __restrict__ w, const float* __restrict__ b,
    const u16* __restrict__ Wswz, const float* __restrict__ a_src,
    const float* __restrict__ a_dst, u16* __restrict__ Xb, int residual,
    u8* __restrict__ T8, float* __restrict__ ES, float* __restrict__ ED) {
  __shared__ __align__(16) u16 sY[16][72];   // 144B rows: 16B-aligned
  const int tid = threadIdx.x;
  const long n0 = (long)blockIdx.x * 16;
  {
    const int node = tid >> 4;
    const int c4 = (tid & 15) << 2;
    const long n = n0 + node;
    const int g = batch[n];
    ushort4 fu = *(const ushort4*)(Fb + n * 64 + c4);
    float4 f = make_float4(bf2f(fu.x), bf2f(fu.y), bf2f(fu.z), bf2f(fu.w));
    float4 mm = *(const float4*)(MM + g * 64 + c4);
    float4 is = *(const float4*)(IS + g * 64 + c4);
    float4 wv = *(const float4*)(w + c4);
    float4 bv = *(const float4*)(b + c4);
    float4 y;
    y.x = fmaf(wv.x * (f.x - mm.x), is.x, bv.x);
    y.y = fmaf(wv.y * (f.y - mm.y), is.y, bv.y);
    y.z = fmaf(wv.z * (f.z - mm.z), is.z, bv.z);
    y.w = fmaf(wv.w * (f.w - mm.w), is.w, bv.w);
    if (residual) {
      ushort4 xo = *(const ushort4*)(Xb + n * 64 + c4);
      y.x += bf2f(xo.x); y.y += bf2f(xo.y); y.z += bf2f(xo.z); y.w += bf2f(xo.w);
    }
    union { u16 s[4]; unsigned long long ll; } pk;
    pk.s[0] = f2bf(y.x); pk.s[1] = f2bf(y.y); pk.s[2] = f2bf(y.z); pk.s[3] = f2bf(y.w);
    *(unsigned long long*)(Xb + n * 64 + c4) = pk.ll;
    *(unsigned long long*)&sY[node][c4] = pk.ll;
  }
  __syncthreads();
  const int lane = tid & 63;
  const int wid = tid >> 6;
  const int grp = lane >> 4, n16 = lane & 15;
  bf16x8 afr[2];
  #pragma unroll
  for (int ks = 0; ks < 2; ++ks)
    afr[ks] = *(const bf16x8*)(&sY[n16][ks * 32 + grp * 8]);
  f32x4 a = {0.f, 0.f, 0.f, 0.f};
  #pragma unroll
  for (int ks = 0; ks < 2; ++ks) {
    bf16x8 bb = *(const bf16x8*)(Wswz + ((size_t)(wid * 2 + ks) * 64 + lane) * 8);
    a = __builtin_amdgcn_mfma_f32_16x16x32_bf16(afr[ks], bb, a, 0, 0, 0);
  }
  const float as_c = a_src[wid * 16 + n16];
  const float ad_c = a_dst[wid * 16 + n16];
  #pragma unroll
  for (int r = 0; r < 4; ++r) {
    const long row = n0 + grp * 4 + r;
    float v = a[r];
    T8[row * 64 + wid * 16 + n16] = f2fp8(v);
    float s = v * as_c;
    float d = v * ad_c;
    s += __shfl_xor(s, 1); s += __shfl_xor(s, 2); s += __shfl_xor(s, 4); s += __shfl_xor(s, 8);
    d += __shfl_xor(d, 1); d += __shfl_xor(d, 2); d += __shfl_xor(d, 4); d += __shfl_xor(d, 8);
    if (n16 == 0) {
      ES[row * 4 + wid] = s;
      ED[row * 4 + wid] = d;
    }
  }
}

// ---------------- last layer: norm + residual (bf16 X) + pooling partials ----------------
__global__ __launch_bounds__(256) void k_norm_res(
    const u16* __restrict__ Fb, const int* __restrict__ batch,
    const float* __restrict__ MM, const float* __restrict__ IS,
    const float* __restrict__ w, const float* __restrict__ b,
    u16* __restrict__ Xb, float* __restrict__ SPp) {
  __shared__ float sS[16][64];
  const int tid = threadIdx.x;
  const long n0 = (long)blockIdx.x * 16;
  const int node = tid >> 4;
  const int c4 = (tid & 15) << 2;
  const long n = n0 + node;
  const int g = batch[n];
  ushort4 fu = *(const ushort4*)(Fb + n * 64 + c4);
  float4 f = make_float4(bf2f(fu.x), bf2f(fu.y), bf2f(fu.z), bf2f(fu.w));
  float4 mm = *(const float4*)(MM + g * 64 + c4);
  float4 is = *(const float4*)(IS + g * 64 + c4);
  float4 wv = *(const float4*)(w + c4);
  float4 bv = *(const float4*)(b + c4);
  float4 y;
  y.x = fmaf(wv.x * (f.x - mm.x), is.x, bv.x);
  y.y = fmaf(wv.y * (f.y - mm.y), is.y, bv.y);
  y.z = fmaf(wv.z * (f.z - mm.z), is.z, bv.z);
  y.w = fmaf(wv.w * (f.w - mm.w), is.w, bv.w);
  ushort4 xo = *(const ushort4*)(Xb + n * 64 + c4);
  y.x += bf2f(xo.x); y.y += bf2f(xo.y); y.z += bf2f(xo.z); y.w += bf2f(xo.w);
  *(float4*)&sS[node][c4] = y;
  __syncthreads();
  // pooling partial sums (per-graph runs over the block's 16 nodes)
  if (tid < 64) {
    const int part = blockIdx.x & (MPART - 1);
    int gprev = batch[n0];
    float fs = 0.f;
    #pragma unroll
    for (int w2 = 0; w2 < 16; ++w2) {
      int gw = batch[n0 + w2];
      if (gw != gprev) {
        atomicAdd(&SPp[((size_t)part * N_GRAPHS + gprev) * 64 + tid], fs);
        fs = 0.f; gprev = gw;
      }
      fs += sS[w2][tid];
    }
    atomicAdd(&SPp[((size_t)part * N_GRAPHS + gprev) * 64 + tid], fs);
  }
}

// ---------------- pooled MLP head (one block) ----------------
__global__ __launch_bounds__(512) void k_mlp(
    const float* __restrict__ SPp, const int* __restrict__ gstart, const float* __restrict__ gf,
    const float* __restrict__ W0, const float* __restrict__ b0,
    const float* __restrict__ lw0, const float* __restrict__ lb0,
    const float* __restrict__ Wg, const float* __restrict__ bg,
    const float* __restrict__ lwg, const float* __restrict__ lbg,
    const float* __restrict__ hW, const float* __restrict__ hb,
    float* __restrict__ out) {
  __shared__ float P[16][88];
  __shared__ float Z[16][32];
  const int tid = threadIdx.x;
  for (int i = tid; i < 16 * 88; i += 512) {
    int g = i / 88, c = i - g * 88;
    float v;
    if (c < 64) {
      float s = 0.f;
      for (int b = 0; b < MPART; ++b) s += SPp[((size_t)b * N_GRAPHS + g) * 64 + c];
      float cnt = fmaxf((float)(gstart[g + 1] - gstart[g]), 1.0f);
      v = s / cnt;
    } else {
      v = gf[g * GDIM + (c - 64)];
    }
    P[g][c] = v;
  }
  __syncthreads();
  const int g = tid >> 5, c = tid & 31;
  float acc = b0[c];
  for (int k = 0; k < 88; ++k) acc = fmaf(P[g][k], W0[k * 32 + c], acc);
  float z = ln32(gelu_exact(acc), lw0[c], lb0[c]);
  for (int l = 0; l < LL; ++l) {
    Z[g][c] = z;
    __syncthreads();
    float a2 = bg[l * 32 + c];
    const float* Wl = Wg + l * 32 * 32;
    for (int k = 0; k < 32; ++k) a2 = fmaf(Z[g][k], Wl[k * 32 + c], a2);
    __syncthreads();
    z = ln32(gelu_exact(a2), lwg[l * 32 + c], lbg[l * 32 + c]) + z;
  }
  Z[g][c] = z * hW[c];
  __syncthreads();
  if (c == 0) {
    float s = 0.f;
    for (int k = 0; k < 32; ++k) s += Z[g][k];
    out[g] = s + hb[0];
  }
}

extern "C" void kernel_launch(void* const* d_in, const int* in_sizes, int n_in,
                              void* d_out, int out_size, void* d_ws, size_t ws_size,
                              hipStream_t stream) {
  const float* x   = (const float*)d_in[0];
  const int*   ei  = (const int*)d_in[1];
  const int* batch = (const int*)d_in[2];
  const float* gf  = (const float*)d_in[3];
  const float* W0  = (const float*)d_in[4];
  const float* as0 = (const float*)d_in[5];
  const float* ad0 = (const float*)d_in[6];
  const float* b0  = (const float*)d_in[7];
  const float* gw0 = (const float*)d_in[8];
  const float* gb0 = (const float*)d_in[9];
  const float* gm0 = (const float*)d_in[10];
  const float* Wg  = (const float*)d_in[11];
  const float* asg = (const float*)d_in[12];
  const float* adg = (const float*)d_in[13];
  const float* bg  = (const float*)d_in[14];
  const float* gwg = (const float*)d_in[15];
  const float* gbg = (const float*)d_in[16];
  const float* gmg = (const float*)d_in[17];
  const float* mW0 = (const float*)d_in[18];
  const float* mb0 = (const float*)d_in[19];
  const float* lw0 = (const float*)d_in[20];
  const float* lb0 = (const float*)d_in[21];
  const float* mWg = (const float*)d_in[22];
  const float* mbg = (const float*)d_in[23];
  const float* lwg = (const float*)d_in[24];
  const float* lbg = (const float*)d_in[25];
  const float* hW  = (const float*)d_in[26];
  const float* hb  = (const float*)d_in[27];
  float* out = (float*)d_out;
  const int* src = ei;
  const int* dst = ei + N_EDGES;

  char* p = (char*)d_ws;
  auto alloc = [&](size_t bytes) {
    char* r = p;
    p += (bytes + 255) & ~(size_t)255;
    return (void*)r;
  };
  u16*   Xb  = (u16*)alloc((size_t)N_NODES * 64 * 2);
  u16*   Fb  = (u16*)alloc((size_t)N_NODES * 64 * 2);
  u8*    T8  = (u8*)alloc((size_t)N_NODES * 64);
  float* ES  = (float*)alloc((size_t)N_NODES * 4 * 4);
  float* ED  = (float*)alloc((size_t)N_NODES * 4 * 4);
  int* ssrc  = (int*)alloc((size_t)N_EDGES * 4);
  int* deg   = (int*)alloc((size_t)N_NODES * 4);
  int* off   = (int*)alloc((size_t)(N_NODES + 1) * 4);
  int* cur   = (int*)alloc((size_t)N_NODES * 4);
  int* bsum  = (int*)alloc(4096);
  int* gstart = (int*)alloc((N_GRAPHS + 1) * 4);
  u16* W0s   = (u16*)alloc((size_t)W0S_ELEMS * 2);
  u16* Wgs   = (u16*)alloc((size_t)GL * WGS_ELEMS * 2);
  float* SPp = (float*)alloc((size_t)MPART * N_GRAPHS * 64 * 4);
  float* SQp = (float*)alloc((size_t)MPART * N_GRAPHS * 64 * 4);
  float* MM  = (float*)alloc(N_GRAPHS * 64 * 4);
  float* IS  = (float*)alloc(N_GRAPHS * 64 * 4);
  (void)ws_size; (void)in_sizes; (void)n_in; (void)out_size;

  const int NB = (N_NODES + 255) / 256;
  hipMemsetAsync(deg, 0, (size_t)N_NODES * 4, stream);
  hipMemsetAsync(SPp, 0, (size_t)MPART * N_GRAPHS * 64 * 4 * 2, stream);  // SPp+SQp contiguous
  k_count_part<<<2048, 256, 0, stream>>>(dst, deg);
  k_block_sums<<<NB, 256, 0, stream>>>(deg, bsum);
  k_scan_bsums<<<1, 512, 0, stream>>>(bsum, NB, off);
  k_scan_final<<<NB, 256, 0, stream>>>(deg, bsum, off, cur);
  k_scatter_part<<<2048, 256, 0, stream>>>(src, dst, cur, ssrc);
  k_graph_starts<<<1, 32, 0, stream>>>(batch, gstart);
  k_prep_w<<<(W0S_ELEMS + GL * WGS_ELEMS + 255) / 256, 256, 0, stream>>>(W0, Wg, W0s, Wgs);

  const int GG = (N_NODES / 16 + 3) / 4;
  k_gemm0<<<GG, 256, 0, stream>>>(x, W0s, as0, ad0, T8, ES, ED);
  for (int l = 0; l < 1 + GL; ++l) {
    const float* bl  = (l == 0) ? b0  : (bg  + (size_t)(l - 1) * 64);
    const float* gwl = (l == 0) ? gw0 : (gwg + (size_t)(l - 1) * 64);
    const float* gbl = (l == 0) ? gb0 : (gbg + (size_t)(l - 1) * 64);
    const float* gml = (l == 0) ? gm0 : (gmg + (size_t)(l - 1) * 64);
    k_edge_agg<<<EBLK, 256, 0, stream>>>(T8, ES, ED, off, ssrc, bl, batch, Fb, SPp, SQp);
    k_stats<<<N_GRAPHS, 256, 0, stream>>>(gstart, gml, SPp, SQp, MM, IS);
    if (l < GL) {
      k_norm_gemm<<<N_NODES / 16, 256, 0, stream>>>(
          Fb, batch, MM, IS, gwl, gbl,
          Wgs + (size_t)l * WGS_ELEMS, asg + (size_t)l * 64, adg + (size_t)l * 64,
          Xb, (l > 0) ? 1 : 0, T8, ES, ED);
    } else {
      k_norm_res<<<N_NODES / 16, 256, 0, stream>>>(Fb, batch, MM, IS, gwl, gbl, Xb, SPp);
    }
  }

  k_mlp<<<1, 512, 0, stream>>>(SPp, gstart, gf, mW0, mb0, lw0, lb0,
                               mWg, mbg, lwg, lbg, hW, hb, out);
}